// Round 2
// baseline (844.571 us; speedup 1.0000x reference)
//
#include <hip/hip_runtime.h>
#include <stdint.h>

// ---------- types ----------
typedef unsigned short bf16_t;
typedef __attribute__((ext_vector_type(8))) short   short8;   // 8 bf16 = 4 VGPRs (MFMA A/B frag)
typedef __attribute__((ext_vector_type(4))) float   floatx4;  // MFMA C/D frag
typedef __attribute__((ext_vector_type(4))) unsigned int   uint4v;
typedef __attribute__((ext_vector_type(4))) unsigned short ushort4v;

#define GAS __attribute__((address_space(1)))
#define LAS __attribute__((address_space(3)))

__device__ __forceinline__ unsigned short f2bf(float f) {
  unsigned u = __float_as_uint(f);
  u += 0x7FFFu + ((u >> 16) & 1u);   // RNE
  return (unsigned short)(u >> 16);
}
__device__ __forceinline__ void store_out(float* p, float v) { *p = v; }
__device__ __forceinline__ void store_out(bf16_t* p, float v) { *p = f2bf(v); }

__device__ __forceinline__ void g2l16(const bf16_t* g, bf16_t* l) {
  // async global->LDS, 16B/lane; LDS dest is wave-uniform base + lane*16
  __builtin_amdgcn_global_load_lds((const GAS uint32_t*)g, (LAS uint32_t*)l, 16, 0, 0);
}

// ---------- fp32 -> bf16 converts ----------
__global__ __launch_bounds__(256) void conv_f32_bf16(const float* __restrict__ s,
                                                     bf16_t* __restrict__ d) {
  size_t i = ((size_t)blockIdx.x * 256 + threadIdx.x) * 4;
  float4 v = *(const float4*)(s + i);
  ushort4v o = { f2bf(v.x), f2bf(v.y), f2bf(v.z), f2bf(v.w) };
  *(ushort4v*)(d + i) = o;
}

__global__ __launch_bounds__(256) void conv_w(const float* __restrict__ w0, const float* __restrict__ w1,
                                              const float* __restrict__ w2, const float* __restrict__ w3,
                                              bf16_t* __restrict__ d) {
  const float* s = blockIdx.y == 0 ? w0 : blockIdx.y == 1 ? w1 : blockIdx.y == 2 ? w2 : w3;
  size_t i = ((size_t)blockIdx.x * 256 + threadIdx.x) * 4;
  float4 v = *(const float4*)(s + i);
  ushort4v o = { f2bf(v.x), f2bf(v.y), f2bf(v.z), f2bf(v.w) };
  *(ushort4v*)(d + (size_t)blockIdx.y * 1048576 + i) = o;
}

// ---------- m97-style GEMM: C[M,N] = A[M,K] * B[N,K]^T (+bias) * scale ----------
// 128x128 tile, BK=32, 4 waves each computing 4x4 tiles of 16x16x32 bf16 MFMA.
// LDS tiles stored in FRAGMENT ORDER: subtile s (16 rows) at s*512 elements;
// within subtile, 16B chunk index = kq*16 + row  (kq = k/8). This makes the
// reader's 16-lane phases sweep contiguous 256B -> zero bank conflicts, while
// global_load_lds keeps its mandatory base+lane*16 LDS pattern (we permute the
// GLOBAL side of the staging instead).
template <typename OutT>
__global__ __launch_bounds__(256) void gemm_bt(
    const bf16_t* __restrict__ A, const bf16_t* __restrict__ B,
    const float* __restrict__ bias, OutT* __restrict__ C,
    int M, int N, int K, long aBat, long bBat, long cBat, float scale)
{
  const int tid  = threadIdx.x;
  const int lane = tid & 63;
  const int wv   = tid >> 6;

  // XCD-aware swizzle: all x-blocks of one y-panel share flat%8 -> same XCD,
  // so the A panel is fetched into that XCD's L2 once instead of 8 times.
  int bx, by;
  {
    const int gx = gridDim.x, gy = gridDim.y;
    const int flat = blockIdx.y * gx + blockIdx.x;
    if ((gy & 7) == 0) {
      const int xcd = flat & 7;
      const int r   = flat >> 3;
      bx = r % gx;
      by = xcd + 8 * (r / gx);
    } else { bx = blockIdx.x; by = blockIdx.y; }
  }
  const int bm = by * 128;
  const int bn = bx * 128;
  A += (size_t)blockIdx.z * aBat;
  B += (size_t)blockIdx.z * bBat;
  C += (size_t)blockIdx.z * cBat;

  __shared__ bf16_t As[128 * 32];
  __shared__ bf16_t Bs[128 * 32];

  const int wm = (wv >> 1) * 64;
  const int wn = (wv & 1) * 64;

  floatx4 zero = {0.0f, 0.0f, 0.0f, 0.0f};
  floatx4 acc[4][4];
#pragma unroll
  for (int i = 0; i < 4; i++)
#pragma unroll
    for (int j = 0; j < 4; j++) acc[i][j] = zero;

  // staging (fragment order): lane l loads global (row = l&15, kq = l>>4)
  const int sr = lane & 15;
  const int sq = (lane >> 4) * 8;
  const bf16_t* gA = A + (size_t)(bm + wv * 32 + sr) * K + sq;
  const bf16_t* gB = B + (size_t)(bn + wv * 32 + sr) * K + sq;
  bf16_t* lA = As + wv * 1024 + lane * 8;   // subtile 2*wv, chunk=lane
  bf16_t* lB = Bs + wv * 1024 + lane * 8;

  const int fr = lane & 15;            // m (or n) within 16-tile
  const int fq = (lane >> 4) * 128;    // element offset of this lane's k-quad

  const int sA = (wv >> 1) * 4;        // first A subtile this wave reads
  const int sB = (wv & 1) * 4;         // first B subtile

  for (int k0 = 0; k0 < K; k0 += 32) {
    g2l16(gA,                  lA);
    g2l16(gA + (size_t)16 * K, lA + 512);
    g2l16(gB,                  lB);
    g2l16(gB + (size_t)16 * K, lB + 512);
    gA += 32; gB += 32;
    __syncthreads();   // vmcnt(0) drain + barrier: tiles visible

    short8 af[4], bfr[4];
#pragma unroll
    for (int i = 0; i < 4; i++)
      af[i] = *(const short8*)(As + (sA + i) * 512 + fq + fr * 8);
#pragma unroll
    for (int i = 0; i < 4; i++)
      bfr[i] = *(const short8*)(Bs + (sB + i) * 512 + fq + fr * 8);
#pragma unroll
    for (int mi = 0; mi < 4; mi++)
#pragma unroll
      for (int ni = 0; ni < 4; ni++)
        acc[mi][ni] = __builtin_amdgcn_mfma_f32_16x16x32_bf16(af[mi], bfr[ni], acc[mi][ni], 0, 0, 0);
    __syncthreads();   // compute done before next staging overwrites LDS
  }

  // epilogue: C/D layout col=lane&15, row=(lane>>4)*4+reg  [verified m89]
  const int er = (lane >> 4) * 4;
  const int ec = lane & 15;
#pragma unroll
  for (int ni = 0; ni < 4; ni++) {
    const int col = bn + wn + ni * 16 + ec;
    const float bval = bias ? bias[col] : 0.0f;
#pragma unroll
    for (int mi = 0; mi < 4; mi++) {
      const int row0 = bm + wm + mi * 16 + er;
#pragma unroll
      for (int r = 0; r < 4; r++) {
        float v = (acc[mi][ni][r] + bval) * scale;
        store_out(C + (size_t)(row0 + r) * N + col, v);
      }
    }
  }
}

// ---------- row softmax in place, bf16 [16384][2048], one block per row ----------
__global__ __launch_bounds__(256) void softmax_rows(bf16_t* __restrict__ S) {
  const int tid = threadIdx.x;
  bf16_t* row = S + (size_t)blockIdx.x * 2048;
  uint4v raw = *(const uint4v*)(row + tid * 8);
  float x[8];
#pragma unroll
  for (int j = 0; j < 4; j++) {
    unsigned w = raw[j];
    x[2 * j]     = __uint_as_float(w << 16);
    x[2 * j + 1] = __uint_as_float(w & 0xFFFF0000u);
  }
  float m = -1e30f;
#pragma unroll
  for (int j = 0; j < 8; j++) m = fmaxf(m, x[j]);
  for (int o = 32; o > 0; o >>= 1) m = fmaxf(m, __shfl_xor(m, o, 64));
  __shared__ float red[4];
  if ((tid & 63) == 0) red[tid >> 6] = m;
  __syncthreads();
  m = fmaxf(fmaxf(red[0], red[1]), fmaxf(red[2], red[3]));

  float e[8];
  float s = 0.0f;
#pragma unroll
  for (int j = 0; j < 8; j++) { e[j] = __expf(x[j] - m); s += e[j]; }
  for (int o = 32; o > 0; o >>= 1) s += __shfl_xor(s, o, 64);
  __syncthreads();
  if ((tid & 63) == 0) red[tid >> 6] = s;
  __syncthreads();
  s = red[0] + red[1] + red[2] + red[3];
  float inv = 1.0f / s;

  uint4v o4;
#pragma unroll
  for (int j = 0; j < 4; j++) {
    unsigned lo = f2bf(e[2 * j] * inv);
    unsigned hi = f2bf(e[2 * j + 1] * inv);
    o4[j] = lo | (hi << 16);
  }
  *(uint4v*)(row + tid * 8) = o4;
}

// ---------- V [b][2048][1024] -> Vt [b][1024][2048], 64x64 LDS tiles ----------
__global__ __launch_bounds__(256) void transpose64(const bf16_t* __restrict__ V,
                                                   bf16_t* __restrict__ Vt) {
  __shared__ bf16_t t[64][72];   // 72: keep 16B alignment (144B row) + conflict break
  const int tid = threadIdx.x;
  const int e0 = blockIdx.x * 64;
  const int s0 = blockIdx.y * 64;
  const size_t bb = (size_t)blockIdx.z * (2048 * 1024);
  const int r = tid >> 2;
  const int c = (tid & 3) * 16;
  const bf16_t* src = V + bb + (size_t)(s0 + r) * 1024 + e0 + c;
  uint4v v0 = *(const uint4v*)src;
  uint4v v1 = *(const uint4v*)(src + 8);
  *(uint4v*)&t[r][c]     = v0;
  *(uint4v*)&t[r][c + 8] = v1;
  __syncthreads();
  __attribute__((aligned(16))) bf16_t vals[16];
#pragma unroll
  for (int j = 0; j < 16; j++) vals[j] = t[c + j][r];
  bf16_t* dst = Vt + bb + (size_t)(e0 + r) * 2048 + s0 + c;
  *(uint4v*)dst       = *(const uint4v*)vals;
  *(uint4v*)(dst + 8) = *(const uint4v*)(vals + 8);
}

// ---------- launch ----------
extern "C" void kernel_launch(void* const* d_in, const int* in_sizes, int n_in,
                              void* d_out, int out_size, void* d_ws, size_t ws_size,
                              hipStream_t stream) {
  const float* target = (const float*)d_in[0];
  const float* source = (const float*)d_in[1];
  const float* Wq = (const float*)d_in[2];
  const float* bq = (const float*)d_in[3];
  const float* Wk = (const float*)d_in[4];
  const float* bk = (const float*)d_in[5];
  const float* Wv = (const float*)d_in[6];
  const float* bv = (const float*)d_in[7];
  const float* Wo = (const float*)d_in[8];
  const float* bo = (const float*)d_in[9];
  float* out = (float*)d_out;

  // workspace layout (200 MB total), with overlays:
  //   [0,32M)      Q bf16
  //   [32M,64M)    K bf16
  //   [64M,96M)    V^T bf16
  //   [96M,104M)   Wq/Wk/Wv/Wo bf16
  //   [104M,136M)  target bf16  } S bf16 (64M) overlays both after QKV GEMMs
  //   [136M,168M)  source bf16  }
  //   [168M,200M)  V row-major bf16; attn-out overlays after transpose
  char* ws = (char*)d_ws;
  bf16_t* Qb  = (bf16_t*)(ws + 0);
  bf16_t* Kb  = (bf16_t*)(ws + 33554432);
  bf16_t* Vt  = (bf16_t*)(ws + 67108864);
  bf16_t* Wb  = (bf16_t*)(ws + 100663296);
  bf16_t* Tb  = (bf16_t*)(ws + 109051904);
  bf16_t* Sb  = Tb;                          // 67,108,864 B spanning Tb+Srcb
  bf16_t* Srb = (bf16_t*)(ws + 142606336);
  bf16_t* Vb  = (bf16_t*)(ws + 176160768);
  bf16_t* AO  = Vb;

  // 1. converts (fp32 -> bf16)
  conv_f32_bf16<<<16384, 256, 0, stream>>>(target, Tb);
  conv_f32_bf16<<<16384, 256, 0, stream>>>(source, Srb);
  conv_w<<<dim3(1024, 4), 256, 0, stream>>>(Wq, Wk, Wv, Wo, Wb);

  // 2. projections: X @ W^T + b   (Q pre-scaled by 1/sqrt(1024))
  gemm_bt<<<dim3(8, 128, 1), 256, 0, stream>>>(Tb,  Wb,           bq, Qb, 16384, 1024, 1024, 0L, 0L, 0L, 0.03125f);
  gemm_bt<<<dim3(8, 128, 1), 256, 0, stream>>>(Srb, Wb + 1048576, bk, Kb, 16384, 1024, 1024, 0L, 0L, 0L, 1.0f);
  gemm_bt<<<dim3(8, 128, 1), 256, 0, stream>>>(Srb, Wb + 2097152, bv, Vb, 16384, 1024, 1024, 0L, 0L, 0L, 1.0f);

  // 3. V -> V^T per batch
  transpose64<<<dim3(16, 32, 8), 256, 0, stream>>>(Vb, Vt);

  // 4. scores S = Qs @ K^T  (per batch)
  gemm_bt<<<dim3(16, 16, 8), 256, 0, stream>>>(Qb, Kb, (const float*)nullptr, Sb,
      2048, 2048, 1024, (long)2048 * 1024, (long)2048 * 1024, (long)2048 * 2048, 1.0f);

  // 5. softmax rows, in place
  softmax_rows<<<16384, 256, 0, stream>>>(Sb);

  // 6. out = P @ V  == P @ (V^T)^T  (per batch)
  gemm_bt<<<dim3(8, 16, 8), 256, 0, stream>>>(Sb, Vt, (const float*)nullptr, AO,
      2048, 1024, 2048, (long)2048 * 2048, (long)1024 * 2048, (long)2048 * 1024, 1.0f);

  // 7. final projection: AO @ Wo^T + bo -> fp32 out
  gemm_bt<<<dim3(8, 128, 1), 256, 0, stream>>>(AO, Wb + 3145728, bo, out,
      16384, 1024, 1024, 0L, 0L, 0L, 1.0f);
}

// Round 3
// 648.753 us; speedup vs baseline: 1.3018x; 1.3018x over previous
//
#include <hip/hip_runtime.h>
#include <stdint.h>

// ---------- types ----------
typedef unsigned short bf16_t;
typedef __attribute__((ext_vector_type(8))) short   short8;   // 8 bf16 = 4 VGPRs (MFMA A/B frag)
typedef __attribute__((ext_vector_type(4))) float   floatx4;  // MFMA C/D frag
typedef __attribute__((ext_vector_type(4))) unsigned int   uint4v;
typedef __attribute__((ext_vector_type(4))) unsigned short ushort4v;

#define GAS __attribute__((address_space(1)))
#define LAS __attribute__((address_space(3)))

__device__ __forceinline__ unsigned short f2bf(float f) {
  unsigned u = __float_as_uint(f);
  u += 0x7FFFu + ((u >> 16) & 1u);   // RNE
  return (unsigned short)(u >> 16);
}
__device__ __forceinline__ void store_out(float* p, float v) { *p = v; }
__device__ __forceinline__ void store_out(bf16_t* p, float v) { *p = f2bf(v); }

__device__ __forceinline__ void g2l16(const bf16_t* g, bf16_t* l) {
  // async global->LDS, 16B/lane; LDS dest is wave-uniform base + lane*16
  __builtin_amdgcn_global_load_lds((const GAS uint32_t*)g, (LAS uint32_t*)l, 16, 0, 0);
}

// ---------- fp32 -> bf16 converts ----------
__global__ __launch_bounds__(256) void conv_f32_bf16(const float* __restrict__ s,
                                                     bf16_t* __restrict__ d) {
  size_t i = ((size_t)blockIdx.x * 256 + threadIdx.x) * 4;
  float4 v = *(const float4*)(s + i);
  ushort4v o = { f2bf(v.x), f2bf(v.y), f2bf(v.z), f2bf(v.w) };
  *(ushort4v*)(d + i) = o;
}

__global__ __launch_bounds__(256) void conv_w(const float* __restrict__ w0, const float* __restrict__ w1,
                                              const float* __restrict__ w2, const float* __restrict__ w3,
                                              bf16_t* __restrict__ d) {
  const float* s = blockIdx.y == 0 ? w0 : blockIdx.y == 1 ? w1 : blockIdx.y == 2 ? w2 : w3;
  size_t i = ((size_t)blockIdx.x * 256 + threadIdx.x) * 4;
  float4 v = *(const float4*)(s + i);
  ushort4v o = { f2bf(v.x), f2bf(v.y), f2bf(v.z), f2bf(v.w) };
  *(ushort4v*)(d + (size_t)blockIdx.y * 1048576 + i) = o;
}

// ---------- m97-style GEMM: C[M,N] = A[M,K] * B[N,K]^T (+bias) * scale ----------
// 128x128 tile, BK=32, 4 waves each computing 4x4 tiles of 16x16x32 bf16 MFMA.
//
// LDS layout (per 16-row subtile, 64 chunks of 16B): chunk(r, q) = r*4 + ((q + (r>>1)) & 3)
//   - staging quads stay GLOBAL-CONTIGUOUS: each lane quad covers one row's full
//     64B (internally q-rotated; the coalescer merges by segment, not lane order)
//     -> 64 VMEM requests per block k-step, same as the fastest (R0) pattern.
//   - reader phase (16 lanes, fixed kq) hits bank-groups 0,4,1,5,2,6,3,7 each
//     exactly twice -> 2-way, which is free on gfx950 (m136).
template <typename OutT>
__global__ __launch_bounds__(256) void gemm_bt(
    const bf16_t* __restrict__ A, const bf16_t* __restrict__ B,
    const float* __restrict__ bias, OutT* __restrict__ C,
    int M, int N, int K, long aBat, long bBat, long cBat, float scale)
{
  const int tid  = threadIdx.x;
  const int lane = tid & 63;
  const int wv   = tid >> 6;

  // XCD-aware swizzle: all x-blocks of one y-panel share flat%8 -> same XCD,
  // so the A panel is fetched into that XCD's L2 once instead of 8 times.
  // (R2: FETCH_SIZE 280 -> 164 MB on the big GEMMs.)
  int bx, by;
  {
    const int gx = gridDim.x, gy = gridDim.y;
    const int flat = blockIdx.y * gx + blockIdx.x;
    if ((gy & 7) == 0) {
      const int xcd = flat & 7;
      const int r   = flat >> 3;
      bx = r % gx;
      by = xcd + 8 * (r / gx);
    } else { bx = blockIdx.x; by = blockIdx.y; }
  }
  const int bm = by * 128;
  const int bn = bx * 128;
  A += (size_t)blockIdx.z * aBat;
  B += (size_t)blockIdx.z * bBat;
  C += (size_t)blockIdx.z * cBat;

  __shared__ bf16_t As[128 * 32];
  __shared__ bf16_t Bs[128 * 32];

  const int wm = (wv >> 1) * 64;
  const int wn = (wv & 1) * 64;

  floatx4 zero = {0.0f, 0.0f, 0.0f, 0.0f};
  floatx4 acc[4][4];
#pragma unroll
  for (int i = 0; i < 4; i++)
#pragma unroll
    for (int j = 0; j < 4; j++) acc[i][j] = zero;

  // staging: wave stages rows [wv*32, wv*32+32), 2 instructions of 16 rows.
  // lane l -> row l>>2, k-quad ((l&3) - (l>>3)) & 3   (quad covers row's 64B)
  const int srow = lane >> 2;                           // 0..15
  const int sq   = (((lane & 3) - (lane >> 3)) & 3) * 8; // swizzled k elem offset
  const bf16_t* gA = A + (size_t)(bm + wv * 32 + srow) * K + sq;
  const bf16_t* gB = B + (size_t)(bn + wv * 32 + srow) * K + sq;
  bf16_t* lA = As + wv * 1024 + lane * 8;   // wave-uniform base + lane*16B
  bf16_t* lB = Bs + wv * 1024 + lane * 8;

  const int fr = lane & 15;            // m (or n) within 16-tile
  const int kq = lane >> 4;            // k-quad of this lane's fragment
  const int foff = fr * 32 + (((kq + (fr >> 1)) & 3) << 3);  // elem offset in subtile

  const int sA = (wv >> 1) * 4;        // first A subtile this wave reads
  const int sB = (wv & 1) * 4;         // first B subtile

  for (int k0 = 0; k0 < K; k0 += 32) {
    g2l16(gA,                  lA);
    g2l16(gA + (size_t)16 * K, lA + 512);
    g2l16(gB,                  lB);
    g2l16(gB + (size_t)16 * K, lB + 512);
    gA += 32; gB += 32;
    __syncthreads();   // vmcnt(0) drain + barrier: tiles visible

    short8 af[4], bfr[4];
#pragma unroll
    for (int i = 0; i < 4; i++)
      af[i] = *(const short8*)(As + (sA + i) * 512 + foff);
#pragma unroll
    for (int i = 0; i < 4; i++)
      bfr[i] = *(const short8*)(Bs + (sB + i) * 512 + foff);
#pragma unroll
    for (int mi = 0; mi < 4; mi++)
#pragma unroll
      for (int ni = 0; ni < 4; ni++)
        acc[mi][ni] = __builtin_amdgcn_mfma_f32_16x16x32_bf16(af[mi], bfr[ni], acc[mi][ni], 0, 0, 0);
    __syncthreads();   // compute done before next staging overwrites LDS
  }

  // epilogue: C/D layout col=lane&15, row=(lane>>4)*4+reg  [verified m89]
  const int er = (lane >> 4) * 4;
  const int ec = lane & 15;
#pragma unroll
  for (int ni = 0; ni < 4; ni++) {
    const int col = bn + wn + ni * 16 + ec;
    const float bval = bias ? bias[col] : 0.0f;
#pragma unroll
    for (int mi = 0; mi < 4; mi++) {
      const int row0 = bm + wm + mi * 16 + er;
#pragma unroll
      for (int r = 0; r < 4; r++) {
        float v = (acc[mi][ni][r] + bval) * scale;
        store_out(C + (size_t)(row0 + r) * N + col, v);
      }
    }
  }
}

// ---------- row softmax in place, bf16 [16384][2048], one block per row ----------
__global__ __launch_bounds__(256) void softmax_rows(bf16_t* __restrict__ S) {
  const int tid = threadIdx.x;
  bf16_t* row = S + (size_t)blockIdx.x * 2048;
  uint4v raw = *(const uint4v*)(row + tid * 8);
  float x[8];
#pragma unroll
  for (int j = 0; j < 4; j++) {
    unsigned w = raw[j];
    x[2 * j]     = __uint_as_float(w << 16);
    x[2 * j + 1] = __uint_as_float(w & 0xFFFF0000u);
  }
  float m = -1e30f;
#pragma unroll
  for (int j = 0; j < 8; j++) m = fmaxf(m, x[j]);
  for (int o = 32; o > 0; o >>= 1) m = fmaxf(m, __shfl_xor(m, o, 64));
  __shared__ float red[4];
  if ((tid & 63) == 0) red[tid >> 6] = m;
  __syncthreads();
  m = fmaxf(fmaxf(red[0], red[1]), fmaxf(red[2], red[3]));

  float e[8];
  float s = 0.0f;
#pragma unroll
  for (int j = 0; j < 8; j++) { e[j] = __expf(x[j] - m); s += e[j]; }
  for (int o = 32; o > 0; o >>= 1) s += __shfl_xor(s, o, 64);
  __syncthreads();
  if ((tid & 63) == 0) red[tid >> 6] = s;
  __syncthreads();
  s = red[0] + red[1] + red[2] + red[3];
  float inv = 1.0f / s;

  uint4v o4;
#pragma unroll
  for (int j = 0; j < 4; j++) {
    unsigned lo = f2bf(e[2 * j] * inv);
    unsigned hi = f2bf(e[2 * j + 1] * inv);
    o4[j] = lo | (hi << 16);
  }
  *(uint4v*)(row + tid * 8) = o4;
}

// ---------- V [b][2048][1024] -> Vt [b][1024][2048], 64x64 LDS tiles ----------
__global__ __launch_bounds__(256) void transpose64(const bf16_t* __restrict__ V,
                                                   bf16_t* __restrict__ Vt) {
  __shared__ bf16_t t[64][72];   // 72: keep 16B alignment (144B row) + conflict break
  const int tid = threadIdx.x;
  const int e0 = blockIdx.x * 64;
  const int s0 = blockIdx.y * 64;
  const size_t bb = (size_t)blockIdx.z * (2048 * 1024);
  const int r = tid >> 2;
  const int c = (tid & 3) * 16;
  const bf16_t* src = V + bb + (size_t)(s0 + r) * 1024 + e0 + c;
  uint4v v0 = *(const uint4v*)src;
  uint4v v1 = *(const uint4v*)(src + 8);
  *(uint4v*)&t[r][c]     = v0;
  *(uint4v*)&t[r][c + 8] = v1;
  __syncthreads();
  __attribute__((aligned(16))) bf16_t vals[16];
#pragma unroll
  for (int j = 0; j < 16; j++) vals[j] = t[c + j][r];
  bf16_t* dst = Vt + bb + (size_t)(e0 + r) * 2048 + s0 + c;
  *(uint4v*)dst       = *(const uint4v*)vals;
  *(uint4v*)(dst + 8) = *(const uint4v*)(vals + 8);
}

// ---------- launch ----------
extern "C" void kernel_launch(void* const* d_in, const int* in_sizes, int n_in,
                              void* d_out, int out_size, void* d_ws, size_t ws_size,
                              hipStream_t stream) {
  const float* target = (const float*)d_in[0];
  const float* source = (const float*)d_in[1];
  const float* Wq = (const float*)d_in[2];
  const float* bq = (const float*)d_in[3];
  const float* Wk = (const float*)d_in[4];
  const float* bk = (const float*)d_in[5];
  const float* Wv = (const float*)d_in[6];
  const float* bv = (const float*)d_in[7];
  const float* Wo = (const float*)d_in[8];
  const float* bo = (const float*)d_in[9];
  float* out = (float*)d_out;

  // workspace layout (200 MB total), with overlays:
  //   [0,32M)      Q bf16
  //   [32M,64M)    K bf16
  //   [64M,96M)    V^T bf16
  //   [96M,104M)   Wq/Wk/Wv/Wo bf16
  //   [104M,136M)  target bf16  } S bf16 (64M) overlays both after QKV GEMMs
  //   [136M,168M)  source bf16  }
  //   [168M,200M)  V row-major bf16; attn-out overlays after transpose
  char* ws = (char*)d_ws;
  bf16_t* Qb  = (bf16_t*)(ws + 0);
  bf16_t* Kb  = (bf16_t*)(ws + 33554432);
  bf16_t* Vt  = (bf16_t*)(ws + 67108864);
  bf16_t* Wb  = (bf16_t*)(ws + 100663296);
  bf16_t* Tb  = (bf16_t*)(ws + 109051904);
  bf16_t* Sb  = Tb;                          // 67,108,864 B spanning Tb+Srcb
  bf16_t* Srb = (bf16_t*)(ws + 142606336);
  bf16_t* Vb  = (bf16_t*)(ws + 176160768);
  bf16_t* AO  = Vb;

  // 1. converts (fp32 -> bf16)
  conv_f32_bf16<<<16384, 256, 0, stream>>>(target, Tb);
  conv_f32_bf16<<<16384, 256, 0, stream>>>(source, Srb);
  conv_w<<<dim3(1024, 4), 256, 0, stream>>>(Wq, Wk, Wv, Wo, Wb);

  // 2. projections: X @ W^T + b   (Q pre-scaled by 1/sqrt(1024))
  gemm_bt<<<dim3(8, 128, 1), 256, 0, stream>>>(Tb,  Wb,           bq, Qb, 16384, 1024, 1024, 0L, 0L, 0L, 0.03125f);
  gemm_bt<<<dim3(8, 128, 1), 256, 0, stream>>>(Srb, Wb + 1048576, bk, Kb, 16384, 1024, 1024, 0L, 0L, 0L, 1.0f);
  gemm_bt<<<dim3(8, 128, 1), 256, 0, stream>>>(Srb, Wb + 2097152, bv, Vb, 16384, 1024, 1024, 0L, 0L, 0L, 1.0f);

  // 3. V -> V^T per batch
  transpose64<<<dim3(16, 32, 8), 256, 0, stream>>>(Vb, Vt);

  // 4. scores S = Qs @ K^T  (per batch)
  gemm_bt<<<dim3(16, 16, 8), 256, 0, stream>>>(Qb, Kb, (const float*)nullptr, Sb,
      2048, 2048, 1024, (long)2048 * 1024, (long)2048 * 1024, (long)2048 * 2048, 1.0f);

  // 5. softmax rows, in place
  softmax_rows<<<16384, 256, 0, stream>>>(Sb);

  // 6. out = P @ V  == P @ (V^T)^T  (per batch)
  gemm_bt<<<dim3(8, 16, 8), 256, 0, stream>>>(Sb, Vt, (const float*)nullptr, AO,
      2048, 1024, 2048, (long)2048 * 2048, (long)1024 * 2048, (long)2048 * 1024, 1.0f);

  // 7. final projection: AO @ Wo^T + bo -> fp32 out
  gemm_bt<<<dim3(8, 128, 1), 256, 0, stream>>>(AO, Wb + 3145728, bo, out,
      16384, 1024, 1024, 0L, 0L, 0L, 1.0f);
}

// Round 4
// 591.850 us; speedup vs baseline: 1.4270x; 1.0961x over previous
//
#include <hip/hip_runtime.h>
#include <stdint.h>

// ---------- types ----------
typedef unsigned short bf16_t;
typedef __attribute__((ext_vector_type(8))) short   short8;   // 8 bf16 = 4 VGPRs (MFMA A/B frag)
typedef __attribute__((ext_vector_type(4))) float   floatx4;  // MFMA C/D frag
typedef __attribute__((ext_vector_type(4))) unsigned int   uint4v;
typedef __attribute__((ext_vector_type(4))) unsigned short ushort4v;

#define GAS __attribute__((address_space(1)))
#define LAS __attribute__((address_space(3)))

__device__ __forceinline__ unsigned short f2bf(float f) {
  unsigned u = __float_as_uint(f);
  u += 0x7FFFu + ((u >> 16) & 1u);   // RNE
  return (unsigned short)(u >> 16);
}
__device__ __forceinline__ void store_out(float* p, float v) { *p = v; }
__device__ __forceinline__ void store_out(bf16_t* p, float v) { *p = f2bf(v); }

__device__ __forceinline__ void g2l16(const bf16_t* g, bf16_t* l) {
  // async global->LDS, 16B/lane; LDS dest is wave-uniform base + lane*16
  __builtin_amdgcn_global_load_lds((const GAS uint32_t*)g, (LAS uint32_t*)l, 16, 0, 0);
}

// ---------- fp32 -> bf16 converts ----------
__global__ __launch_bounds__(256) void conv_f32_bf16(const float* __restrict__ s,
                                                     bf16_t* __restrict__ d) {
  size_t i = ((size_t)blockIdx.x * 256 + threadIdx.x) * 4;
  float4 v = *(const float4*)(s + i);
  ushort4v o = { f2bf(v.x), f2bf(v.y), f2bf(v.z), f2bf(v.w) };
  *(ushort4v*)(d + i) = o;
}

__global__ __launch_bounds__(256) void conv_w(const float* __restrict__ w0, const float* __restrict__ w1,
                                              const float* __restrict__ w2, const float* __restrict__ w3,
                                              bf16_t* __restrict__ d) {
  const float* s = blockIdx.y == 0 ? w0 : blockIdx.y == 1 ? w1 : blockIdx.y == 2 ? w2 : w3;
  size_t i = ((size_t)blockIdx.x * 256 + threadIdx.x) * 4;
  float4 v = *(const float4*)(s + i);
  ushort4v o = { f2bf(v.x), f2bf(v.y), f2bf(v.z), f2bf(v.w) };
  *(ushort4v*)(d + (size_t)blockIdx.y * 1048576 + i) = o;
}

// ---------- GEMM: C[M,N] = A[M,K] * B[N,K]^T (+bias) * scale ----------
// 128x128 tile, BK=64 (R4: doubles MFMA work per barrier vs m97's BK=32 to
// amortize the staging-load latency exposed at __syncthreads; we are pinned
// at 2 blocks/CU by the 140-reg wave so barrier amortization is the lever).
// 4 waves, each computing a 64x64 tile as 4x4 of 16x16x32 bf16 MFMA.
//
// LDS layout: row R (of 128) occupies elems [R*64, R*64+64); within a row the
// eight 16B k-chunks are stored rotated: chunk q at slot (q + (R&7)) & 7.
//   - staging octets stay GLOBAL-CONTIGUOUS: 8 lanes cover one row's 128B
//     (internally rotated) -> same VMEM request count as the fast R0 pattern.
//   - every 8-consecutive-lane ds_read phase hits 8 distinct bank groups
//     -> 0 conflicts (verified by the R3 measurement of the same scheme).
template <typename OutT>
__global__ __launch_bounds__(256) void gemm_bt(
    const bf16_t* __restrict__ A, const bf16_t* __restrict__ B,
    const float* __restrict__ bias, OutT* __restrict__ C,
    int M, int N, int K, long aBat, long bBat, long cBat, float scale)
{
  const int tid  = threadIdx.x;
  const int lane = tid & 63;
  const int wv   = tid >> 6;

  // XCD-aware swizzle: all x-blocks of one y-panel share flat%8 -> same XCD,
  // so the A panel is fetched into that XCD's L2 once instead of 8 times.
  // (R2: FETCH_SIZE 280 -> 164 MB on the big GEMMs.)
  int bx, by;
  {
    const int gx = gridDim.x, gy = gridDim.y;
    const int flat = blockIdx.y * gx + blockIdx.x;
    if ((gy & 7) == 0) {
      const int xcd = flat & 7;
      const int r   = flat >> 3;
      bx = r % gx;
      by = xcd + 8 * (r / gx);
    } else { bx = blockIdx.x; by = blockIdx.y; }
  }
  const int bm = by * 128;
  const int bn = bx * 128;
  A += (size_t)blockIdx.z * aBat;
  B += (size_t)blockIdx.z * bBat;
  C += (size_t)blockIdx.z * cBat;

  __shared__ bf16_t As[128 * 64];   // 16 KB
  __shared__ bf16_t Bs[128 * 64];   // 16 KB

  const int wm = (wv >> 1) * 64;
  const int wn = (wv & 1) * 64;

  floatx4 zero = {0.0f, 0.0f, 0.0f, 0.0f};
  floatx4 acc[4][4];
#pragma unroll
  for (int i = 0; i < 4; i++)
#pragma unroll
    for (int j = 0; j < 4; j++) acc[i][j] = zero;

  // staging: wave stages rows [wv*32, wv*32+32), 4 instrs of 8 rows each.
  // lane -> row (lane>>3), k-chunk q = ((lane&7) - (lane>>3)) & 7, so that
  // LDS slot (lane&7) == (q + row&7) & 7.
  const int r8 = lane >> 3;
  const int sq = (((lane & 7) - r8) & 7) * 8;     // k elem offset
  const bf16_t* gA = A + (size_t)(bm + wv * 32 + r8) * K + sq;
  const bf16_t* gB = B + (size_t)(bn + wv * 32 + r8) * K + sq;
  bf16_t* lA = As + wv * 2048 + lane * 8;   // wave-uniform base + lane*16B
  bf16_t* lB = Bs + wv * 2048 + lane * 8;

  const int fr = lane & 15;            // m (or n) within 16-tile
  const int kq = lane >> 4;            // k-quad (0..3) of this lane's fragment
  const int frow  = fr * 64;
  const int slot0 = (((kq     + (fr & 7)) & 7) << 3);  // kk=0  phase
  const int slot1 = (((kq + 4 + (fr & 7)) & 7) << 3);  // kk=32 phase

  const int sA = (wv >> 1) * 4;        // first A subtile (16 rows = 1024 elems)
  const int sB = (wv & 1) * 4;

  for (int k0 = 0; k0 < K; k0 += 64) {
#pragma unroll
    for (int i = 0; i < 4; i++) {
      g2l16(gA + (size_t)(i * 8) * K, lA + i * 512);
      g2l16(gB + (size_t)(i * 8) * K, lB + i * 512);
    }
    gA += 64; gB += 64;
    __syncthreads();   // vmcnt(0) drain + barrier: tiles visible

    {
      short8 af[4], bfr[4];
#pragma unroll
      for (int i = 0; i < 4; i++)
        af[i] = *(const short8*)(As + (sA + i) * 1024 + frow + slot0);
#pragma unroll
      for (int i = 0; i < 4; i++)
        bfr[i] = *(const short8*)(Bs + (sB + i) * 1024 + frow + slot0);
#pragma unroll
      for (int mi = 0; mi < 4; mi++)
#pragma unroll
        for (int ni = 0; ni < 4; ni++)
          acc[mi][ni] = __builtin_amdgcn_mfma_f32_16x16x32_bf16(af[mi], bfr[ni], acc[mi][ni], 0, 0, 0);
    }
    {
      short8 af[4], bfr[4];
#pragma unroll
      for (int i = 0; i < 4; i++)
        af[i] = *(const short8*)(As + (sA + i) * 1024 + frow + slot1);
#pragma unroll
      for (int i = 0; i < 4; i++)
        bfr[i] = *(const short8*)(Bs + (sB + i) * 1024 + frow + slot1);
#pragma unroll
      for (int mi = 0; mi < 4; mi++)
#pragma unroll
        for (int ni = 0; ni < 4; ni++)
          acc[mi][ni] = __builtin_amdgcn_mfma_f32_16x16x32_bf16(af[mi], bfr[ni], acc[mi][ni], 0, 0, 0);
    }
    __syncthreads();   // compute done before next staging overwrites LDS
  }

  // epilogue: C/D layout col=lane&15, row=(lane>>4)*4+reg  [verified m89]
  const int er = (lane >> 4) * 4;
  const int ec = lane & 15;
#pragma unroll
  for (int ni = 0; ni < 4; ni++) {
    const int col = bn + wn + ni * 16 + ec;
    const float bval = bias ? bias[col] : 0.0f;
#pragma unroll
    for (int mi = 0; mi < 4; mi++) {
      const int row0 = bm + wm + mi * 16 + er;
#pragma unroll
      for (int r = 0; r < 4; r++) {
        float v = (acc[mi][ni][r] + bval) * scale;
        store_out(C + (size_t)(row0 + r) * N + col, v);
      }
    }
  }
}

// ---------- row softmax in place, bf16 [16384][2048], one block per row ----------
__global__ __launch_bounds__(256) void softmax_rows(bf16_t* __restrict__ S) {
  const int tid = threadIdx.x;
  bf16_t* row = S + (size_t)blockIdx.x * 2048;
  uint4v raw = *(const uint4v*)(row + tid * 8);
  float x[8];
#pragma unroll
  for (int j = 0; j < 4; j++) {
    unsigned w = raw[j];
    x[2 * j]     = __uint_as_float(w << 16);
    x[2 * j + 1] = __uint_as_float(w & 0xFFFF0000u);
  }
  float m = -1e30f;
#pragma unroll
  for (int j = 0; j < 8; j++) m = fmaxf(m, x[j]);
  for (int o = 32; o > 0; o >>= 1) m = fmaxf(m, __shfl_xor(m, o, 64));
  __shared__ float red[4];
  if ((tid & 63) == 0) red[tid >> 6] = m;
  __syncthreads();
  m = fmaxf(fmaxf(red[0], red[1]), fmaxf(red[2], red[3]));

  float e[8];
  float s = 0.0f;
#pragma unroll
  for (int j = 0; j < 8; j++) { e[j] = __expf(x[j] - m); s += e[j]; }
  for (int o = 32; o > 0; o >>= 1) s += __shfl_xor(s, o, 64);
  __syncthreads();
  if ((tid & 63) == 0) red[tid >> 6] = s;
  __syncthreads();
  s = red[0] + red[1] + red[2] + red[3];
  float inv = 1.0f / s;

  uint4v o4;
#pragma unroll
  for (int j = 0; j < 4; j++) {
    unsigned lo = f2bf(e[2 * j] * inv);
    unsigned hi = f2bf(e[2 * j + 1] * inv);
    o4[j] = lo | (hi << 16);
  }
  *(uint4v*)(row + tid * 8) = o4;
}

// ---------- V [b][2048][1024] -> Vt [b][1024][2048], 64x64 LDS tiles ----------
__global__ __launch_bounds__(256) void transpose64(const bf16_t* __restrict__ V,
                                                   bf16_t* __restrict__ Vt) {
  __shared__ bf16_t t[64][72];   // 72: keep 16B alignment (144B row) + conflict break
  const int tid = threadIdx.x;
  const int e0 = blockIdx.x * 64;
  const int s0 = blockIdx.y * 64;
  const size_t bb = (size_t)blockIdx.z * (2048 * 1024);
  const int r = tid >> 2;
  const int c = (tid & 3) * 16;
  const bf16_t* src = V + bb + (size_t)(s0 + r) * 1024 + e0 + c;
  uint4v v0 = *(const uint4v*)src;
  uint4v v1 = *(const uint4v*)(src + 8);
  *(uint4v*)&t[r][c]     = v0;
  *(uint4v*)&t[r][c + 8] = v1;
  __syncthreads();
  __attribute__((aligned(16))) bf16_t vals[16];
#pragma unroll
  for (int j = 0; j < 16; j++) vals[j] = t[c + j][r];
  bf16_t* dst = Vt + bb + (size_t)(e0 + r) * 2048 + s0 + c;
  *(uint4v*)dst       = *(const uint4v*)vals;
  *(uint4v*)(dst + 8) = *(const uint4v*)(vals + 8);
}

// ---------- launch ----------
extern "C" void kernel_launch(void* const* d_in, const int* in_sizes, int n_in,
                              void* d_out, int out_size, void* d_ws, size_t ws_size,
                              hipStream_t stream) {
  const float* target = (const float*)d_in[0];
  const float* source = (const float*)d_in[1];
  const float* Wq = (const float*)d_in[2];
  const float* bq = (const float*)d_in[3];
  const float* Wk = (const float*)d_in[4];
  const float* bk = (const float*)d_in[5];
  const float* Wv = (const float*)d_in[6];
  const float* bv = (const float*)d_in[7];
  const float* Wo = (const float*)d_in[8];
  const float* bo = (const float*)d_in[9];
  float* out = (float*)d_out;

  // workspace layout (200 MB total), with overlays:
  //   [0,32M)      Q bf16
  //   [32M,64M)    K bf16
  //   [64M,96M)    V^T bf16
  //   [96M,104M)   Wq/Wk/Wv/Wo bf16
  //   [104M,136M)  target bf16  } S bf16 (64M) overlays both after QKV GEMMs
  //   [136M,168M)  source bf16  }
  //   [168M,200M)  V row-major bf16; attn-out overlays after transpose
  char* ws = (char*)d_ws;
  bf16_t* Qb  = (bf16_t*)(ws + 0);
  bf16_t* Kb  = (bf16_t*)(ws + 33554432);
  bf16_t* Vt  = (bf16_t*)(ws + 67108864);
  bf16_t* Wb  = (bf16_t*)(ws + 100663296);
  bf16_t* Tb  = (bf16_t*)(ws + 109051904);
  bf16_t* Sb  = Tb;                          // 67,108,864 B spanning Tb+Srcb
  bf16_t* Srb = (bf16_t*)(ws + 142606336);
  bf16_t* Vb  = (bf16_t*)(ws + 176160768);
  bf16_t* AO  = Vb;

  // 1. converts (fp32 -> bf16)
  conv_f32_bf16<<<16384, 256, 0, stream>>>(target, Tb);
  conv_f32_bf16<<<16384, 256, 0, stream>>>(source, Srb);
  conv_w<<<dim3(1024, 4), 256, 0, stream>>>(Wq, Wk, Wv, Wo, Wb);

  // 2. projections: X @ W^T + b   (Q pre-scaled by 1/sqrt(1024))
  gemm_bt<<<dim3(8, 128, 1), 256, 0, stream>>>(Tb,  Wb,           bq, Qb, 16384, 1024, 1024, 0L, 0L, 0L, 0.03125f);
  gemm_bt<<<dim3(8, 128, 1), 256, 0, stream>>>(Srb, Wb + 1048576, bk, Kb, 16384, 1024, 1024, 0L, 0L, 0L, 1.0f);
  gemm_bt<<<dim3(8, 128, 1), 256, 0, stream>>>(Srb, Wb + 2097152, bv, Vb, 16384, 1024, 1024, 0L, 0L, 0L, 1.0f);

  // 3. V -> V^T per batch
  transpose64<<<dim3(16, 32, 8), 256, 0, stream>>>(Vb, Vt);

  // 4. scores S = Qs @ K^T  (per batch)
  gemm_bt<<<dim3(16, 16, 8), 256, 0, stream>>>(Qb, Kb, (const float*)nullptr, Sb,
      2048, 2048, 1024, (long)2048 * 1024, (long)2048 * 1024, (long)2048 * 2048, 1.0f);

  // 5. softmax rows, in place
  softmax_rows<<<16384, 256, 0, stream>>>(Sb);

  // 6. out = P @ V  == P @ (V^T)^T  (per batch)
  gemm_bt<<<dim3(8, 16, 8), 256, 0, stream>>>(Sb, Vt, (const float*)nullptr, AO,
      2048, 1024, 2048, (long)2048 * 2048, (long)1024 * 2048, (long)2048 * 1024, 1.0f);

  // 7. final projection: AO @ Wo^T + bo -> fp32 out
  gemm_bt<<<dim3(8, 128, 1), 256, 0, stream>>>(AO, Wb + 3145728, bo, out,
      16384, 1024, 1024, 0L, 0L, 0L, 1.0f);
}